// Round 4
// baseline (507.998 us; speedup 1.0000x reference)
//
#include <hip/hip_runtime.h>
#include <hip/hip_bf16.h>

#define S_LEN  2048
#define BATCH  2
#define NH     16
#define HD     128
#define HIDDEN 2048
#define MROWS  (BATCH*S_LEN)   // 4096

typedef __attribute__((ext_vector_type(8))) short bf16x8;
typedef __attribute__((ext_vector_type(4))) float f32x4;

__device__ __forceinline__ float bf2f(short s) {
    union { float f; unsigned int u; } v;
    v.u = ((unsigned int)(unsigned short)s) << 16;
    return v.f;
}
__device__ __forceinline__ short f2bf(float f) {
    union { float f; unsigned int u; } v;
    v.f = f;
    unsigned int r = v.u + 0x7fffu + ((v.u >> 16) & 1u);   // RNE, inputs never NaN
    return (short)(r >> 16);
}
__device__ __forceinline__ f32x4 mfma16(bf16x8 a, bf16x8 b, f32x4 c) {
    return __builtin_amdgcn_mfma_f32_16x16x32_bf16(a, b, c, 0, 0, 0);
}
__device__ __forceinline__ void gload16(const void* g, void* l) {
    __builtin_amdgcn_global_load_lds(
        (const __attribute__((address_space(1))) void*)g,
        (__attribute__((address_space(3))) void*)l, 16, 0, 0);
}

// ---------------------------------------------------------------------------
// Cast fp32 -> bf16: hidden (2 x 4M segs), wq, wk, wv, wo (1 seg each).
// ---------------------------------------------------------------------------
#define SEG (4194304)
__global__ void cast_k(const float* hs, const float* wq, const float* wk,
                       const float* wv, const float* wo, short* dst)
{
    size_t i = ((size_t)blockIdx.x * 256 + threadIdx.x) * 8;
    int seg = (int)(i >> 22);
    const float* s;
    size_t off;
    if (seg < 2)      { s = hs; off = i; }
    else if (seg == 2){ s = wq; off = i - 2 * (size_t)SEG; }
    else if (seg == 3){ s = wk; off = i - 3 * (size_t)SEG; }
    else if (seg == 4){ s = wv; off = i - 4 * (size_t)SEG; }
    else              { s = wo; off = i - 5 * (size_t)SEG; }
    f32x4 lo = *(const f32x4*)(s + off);
    f32x4 hi = *(const f32x4*)(s + off + 4);
    short v[8];
#pragma unroll
    for (int j = 0; j < 4; ++j) { v[j] = f2bf(lo[j]); v[4 + j] = f2bf(hi[j]); }
    *(bf16x8*)(dst + i) = *(bf16x8*)v;
}

// ---------------------------------------------------------------------------
// GEMM: C[M][N] = A[M][K] * W[N][K]^T, bf16 (m97 structure).
// ---------------------------------------------------------------------------
template<int MODE>
__global__ __launch_bounds__(256, 4)
void gemm_bt(const short* A, const short* W0, const short* W1, const short* W2,
             short* Oq, short* Ok, short* Ov, float* Of)
{
    __shared__ short smem[2 * 128 * 64];
    short* As = smem;
    short* Bs = smem + 128 * 64;

    const int tid  = threadIdx.x;
    const int lane = tid & 63;
    const int wv   = tid >> 6;
    const int wr   = wv >> 1, wc = wv & 1;
    const int fr   = lane & 15, fg = lane >> 4;

    const int mt = blockIdx.x;
    int nt = blockIdx.y;
    const short* W = W0;
    short* Ob = Oq;
    int osel = 0;
    if (MODE == 0) {
        osel = nt >> 4; nt &= 15;
        W  = (osel == 0) ? W0 : (osel == 1) ? W1 : W2;
        Ob = (osel == 0) ? Oq : (osel == 1) ? Ok : Ov;
    }
    const int row0 = mt * 128, col0 = nt * 128;
    const int sr = tid >> 3, sb = tid & 7;

    f32x4 acc[4][4];
#pragma unroll
    for (int m = 0; m < 4; ++m)
#pragma unroll
        for (int n = 0; n < 4; ++n) acc[m][n] = (f32x4){0.f, 0.f, 0.f, 0.f};

    for (int k0 = 0; k0 < HIDDEN; k0 += 64) {
        __syncthreads();
#pragma unroll
        for (int it = 0; it < 4; ++it) {
            int r = it * 32 + sr;
            gload16(A + (size_t)(row0 + r) * HIDDEN + k0 + ((sb ^ (r & 7)) * 8),
                    (char*)As + (it * 256 + wv * 64) * 16);
        }
#pragma unroll
        for (int it = 0; it < 4; ++it) {
            int r = it * 32 + sr;
            gload16(W + (size_t)(col0 + r) * HIDDEN + k0 + ((sb ^ (r & 7)) * 8),
                    (char*)Bs + (it * 256 + wv * 64) * 16);
        }
        __syncthreads();
#pragma unroll
        for (int ks = 0; ks < 2; ++ks) {
            bf16x8 a[4], b[4];
#pragma unroll
            for (int m = 0; m < 4; ++m) {
                int r = wr * 64 + m * 16 + fr;
                a[m] = *(const bf16x8*)&As[r * 64 + (((ks * 4 + fg) ^ (r & 7)) * 8)];
            }
#pragma unroll
            for (int n = 0; n < 4; ++n) {
                int r = wc * 64 + n * 16 + fr;
                b[n] = *(const bf16x8*)&Bs[r * 64 + (((ks * 4 + fg) ^ (r & 7)) * 8)];
            }
#pragma unroll
            for (int m = 0; m < 4; ++m)
#pragma unroll
                for (int n = 0; n < 4; ++n)
                    acc[m][n] = mfma16(a[m], b[n], acc[m][n]);
        }
    }

    if (MODE == 0 && osel == 2) {
        __syncthreads();
#pragma unroll
        for (int m = 0; m < 4; ++m)
#pragma unroll
            for (int j = 0; j < 4; ++j) {
                int row = wr * 64 + m * 16 + fg * 4 + j;
#pragma unroll
                for (int n = 0; n < 4; ++n) {
                    int col = wc * 64 + n * 16 + fr;
                    smem[col * 128 + (((row >> 3) ^ (col & 15)) * 8) + (row & 7)] =
                        f2bf(acc[m][n][j]);
                }
            }
        __syncthreads();
        const int b_ = row0 >> 11;
        const int bh = b_ * NH + nt;
        const int s0 = row0 & (S_LEN - 1);
#pragma unroll
        for (int it = 0; it < 8; ++it) {
            int c = it * 256 + tid;
            int d = c >> 4, sbk = c & 15;
            bf16x8 vv = *(const bf16x8*)&smem[d * 128 + ((sbk ^ (d & 15)) * 8)];
            *(bf16x8*)(Ov + ((size_t)bh * HD + d) * S_LEN + s0 + sbk * 8) = vv;
        }
    } else {
#pragma unroll
        for (int m = 0; m < 4; ++m)
#pragma unroll
            for (int j = 0; j < 4; ++j) {
                int mrow = row0 + wr * 64 + m * 16 + fg * 4 + j;
#pragma unroll
                for (int n = 0; n < 4; ++n) {
                    int col = col0 + wc * 64 + n * 16 + fr;
                    float val = acc[m][n][j];
                    if (MODE == 0) {
                        int b_ = mrow >> 11, s = mrow & (S_LEN - 1);
                        int h = col >> 7, d = col & (HD - 1);
                        Ob[((size_t)(b_ * NH + h) * S_LEN + s) * HD + d] = f2bf(val);
                    } else {
                        Of[(size_t)mrow * HIDDEN + col] = val;
                    }
                }
            }
    }
}

// ---------------------------------------------------------------------------
__global__ void rope_table_k(float* tab)
{
    int i = blockIdx.x * 256 + threadIdx.x;
    if (i >= S_LEN * 64) return;
    int s = i >> 6, d = i & 63;
    float inv = 1.0f / powf(10000.0f, (float)d * (1.0f / 64.0f));
    float ang = (float)s * inv;
    tab[2 * i]     = cosf(ang);
    tab[2 * i + 1] = sinf(ang);
}

__global__ void rope_apply_k(short* Q, short* K, const float* tab)
{
    int i = blockIdx.x * 256 + threadIdx.x;
    int d8 = i & 7;
    int s  = (i >> 3) & (S_LEN - 1);
    int bh = i >> 14;
    size_t base = ((size_t)bh * S_LEN + s) * HD + d8 * 8;
    const float* tp = tab + (s * 64 + d8 * 8) * 2;
    f32x4 t[4];
#pragma unroll
    for (int j = 0; j < 4; ++j) t[j] = *(const f32x4*)(tp + j * 4);

    bf16x8 q1 = *(bf16x8*)(Q + base), q2 = *(bf16x8*)(Q + base + 64);
    bf16x8 k1 = *(bf16x8*)(K + base), k2 = *(bf16x8*)(K + base + 64);
    short oq1[8], oq2[8], ok1[8], ok2[8];
    const float qs = 0.08838834764831845f;
#pragma unroll
    for (int j = 0; j < 8; ++j) {
        float c  = t[j >> 1][(j & 1) * 2];
        float sn = t[j >> 1][(j & 1) * 2 + 1];
        float a1 = bf2f(q1[j]), a2 = bf2f(q2[j]);
        oq1[j] = f2bf((a1 * c - a2 * sn) * qs);
        oq2[j] = f2bf((a2 * c + a1 * sn) * qs);
        float b1 = bf2f(k1[j]), b2 = bf2f(k2[j]);
        ok1[j] = f2bf(b1 * c - b2 * sn);
        ok2[j] = f2bf(b2 * c + b1 * sn);
    }
    *(bf16x8*)(Q + base)      = *(bf16x8*)oq1;
    *(bf16x8*)(Q + base + 64) = *(bf16x8*)oq2;
    *(bf16x8*)(K + base)      = *(bf16x8*)ok1;
    *(bf16x8*)(K + base + 64) = *(bf16x8*)ok2;
}

// ---------------------------------------------------------------------------
// Causal flash attention, NO K/V LDS staging (K/V are L2-resident: 1 MB/bh,
// 16 qt-blocks per bh land on the same XCD). Grid: (32 bh, 16 qt).
// 4 independent waves x 32 q-rows; no __syncthreads in the loop.
// K [bh][s][d]; V [bh][d][s] (transposed). KV tile = 64.
// ---------------------------------------------------------------------------
__global__ __launch_bounds__(256, 2)
void attn_k(const short* Q, const short* K, const short* Vt, short* AO)
{
    __shared__ short Ps[4][32 * 64];    // 16 KB: per-wave P; blk^(ql&7)

    const int tid = threadIdx.x, lane = tid & 63, wv = tid >> 6;
    const int fr = lane & 15, fg = lane >> 4;
    const int bh = blockIdx.x;
    const int qt = 15 - blockIdx.y;     // long blocks dispatch first

    const short* Qb = Q  + (size_t)bh * S_LEN * HD;
    const short* Kb = K  + (size_t)bh * S_LEN * HD;
    const short* Vb = Vt + (size_t)bh * HD * S_LEN;
    const int qbase = qt * 128 + wv * 32;

    bf16x8 qf[2][4];
#pragma unroll
    for (int mi = 0; mi < 2; ++mi)
#pragma unroll
        for (int ks = 0; ks < 4; ++ks)
            qf[mi][ks] = *(const bf16x8*)(Qb + (size_t)(qbase + mi * 16 + fr) * HD
                                          + ks * 32 + fg * 8);

    f32x4 o[2][8];
    float mrun[2][4], lrun[2][4];
#pragma unroll
    for (int mi = 0; mi < 2; ++mi) {
#pragma unroll
        for (int nd = 0; nd < 8; ++nd) o[mi][nd] = (f32x4){0.f, 0.f, 0.f, 0.f};
#pragma unroll
        for (int j = 0; j < 4; ++j) { mrun[mi][j] = -1e30f; lrun[mi][j] = 0.f; }
    }

    const int ntw = (qbase + 95) >> 6;  // tiles with kb <= qbase+31

    for (int t = 0; t < ntw; ++t) {
        const int kb = t * 64;
        // ---- QK^T: K fragments straight from global (L2-resident) ----
        f32x4 sc[2][4];
#pragma unroll
        for (int mi = 0; mi < 2; ++mi)
#pragma unroll
            for (int ni = 0; ni < 4; ++ni) sc[mi][ni] = (f32x4){0.f, 0.f, 0.f, 0.f};
#pragma unroll
        for (int ks = 0; ks < 4; ++ks) {
            bf16x8 kf[4];
#pragma unroll
            for (int ni = 0; ni < 4; ++ni)
                kf[ni] = *(const bf16x8*)(Kb + (size_t)(kb + ni * 16 + fr) * HD
                                          + ks * 32 + fg * 8);
#pragma unroll
            for (int mi = 0; mi < 2; ++mi)
#pragma unroll
                for (int ni = 0; ni < 4; ++ni)
                    sc[mi][ni] = mfma16(qf[mi][ks], kf[ni], sc[mi][ni]);
        }
        const bool need_mask = (kb + 63 > qbase);
        // ---- online softmax ----
#pragma unroll
        for (int mi = 0; mi < 2; ++mi) {
#pragma unroll
            for (int j = 0; j < 4; ++j) {
                int qrow = qbase + mi * 16 + fg * 4 + j;
                if (need_mask) {
#pragma unroll
                    for (int ni = 0; ni < 4; ++ni) {
                        int kcol = kb + ni * 16 + fr;
                        if (kcol > qrow) sc[mi][ni][j] = -1e30f;
                    }
                }
                float mx = fmaxf(fmaxf(sc[mi][0][j], sc[mi][1][j]),
                                 fmaxf(sc[mi][2][j], sc[mi][3][j]));
                mx = fmaxf(mx, __shfl_xor(mx, 1));
                mx = fmaxf(mx, __shfl_xor(mx, 2));
                mx = fmaxf(mx, __shfl_xor(mx, 4));
                mx = fmaxf(mx, __shfl_xor(mx, 8));
                if (mx > mrun[mi][j]) {     // rescale only on new max (exact)
                    float scale = __expf(mrun[mi][j] - mx);
                    mrun[mi][j] = mx;
                    lrun[mi][j] *= scale;
#pragma unroll
                    for (int nd = 0; nd < 8; ++nd) o[mi][nd][j] *= scale;
                }
                float m_ = mrun[mi][j];
                float rs = 0.f;
                int ql = mi * 16 + fg * 4 + j;
#pragma unroll
                for (int ni = 0; ni < 4; ++ni) {
                    float p = __expf(sc[mi][ni][j] - m_);
                    rs += p;
                    int kl = ni * 16 + fr;
                    Ps[wv][ql * 64 + (((kl >> 3) ^ (ql & 7)) * 8) + (kl & 7)] =
                        f2bf(p);
                }
                rs += __shfl_xor(rs, 1);
                rs += __shfl_xor(rs, 2);
                rs += __shfl_xor(rs, 4);
                rs += __shfl_xor(rs, 8);
                lrun[mi][j] += rs;
            }
        }
        asm volatile("s_waitcnt lgkmcnt(0)" ::: "memory");
        // ---- P @ V: V fragments straight from global ----
        bf16x8 pa[2][2];
#pragma unroll
        for (int mi = 0; mi < 2; ++mi) {
            int ql = mi * 16 + fr;
#pragma unroll
            for (int ks = 0; ks < 2; ++ks)
                pa[mi][ks] = *(const bf16x8*)&Ps[wv][ql * 64 + (((ks * 4 + fg) ^ (ql & 7)) * 8)];
        }
#pragma unroll
        for (int nd = 0; nd < 8; ++nd) {
            int d = nd * 16 + fr;
#pragma unroll
            for (int ks = 0; ks < 2; ++ks) {
                bf16x8 vf = *(const bf16x8*)(Vb + (size_t)d * S_LEN + kb
                                             + ks * 32 + fg * 8);
#pragma unroll
                for (int mi = 0; mi < 2; ++mi)
                    o[mi][nd] = mfma16(pa[mi][ks], vf, o[mi][nd]);
            }
        }
    }

    const int b_ = bh >> 4, h = bh & 15;
#pragma unroll
    for (int mi = 0; mi < 2; ++mi)
#pragma unroll
        for (int j = 0; j < 4; ++j) {
            float inv = 1.0f / lrun[mi][j];
            int srow = qbase + mi * 16 + fg * 4 + j;
#pragma unroll
            for (int nd = 0; nd < 8; ++nd) {
                int col = h * HD + nd * 16 + fr;
                AO[((size_t)b_ * S_LEN + srow) * HIDDEN + col] =
                    f2bf(o[mi][nd][j] * inv);
            }
        }
}

// ---------------------------------------------------------------------------
extern "C" void kernel_launch(void* const* d_in, const int* in_sizes, int n_in,
                              void* d_out, int out_size, void* d_ws, size_t ws_size,
                              hipStream_t stream)
{
    const float* hs = (const float*)d_in[0];
    const float* wq = (const float*)d_in[1];
    const float* wk = (const float*)d_in[2];
    const float* wvp = (const float*)d_in[3];
    const float* wo = (const float*)d_in[4];
    float* out = (float*)d_out;

    char* ws = (char*)d_ws;
    short* CB  = (short*)ws;
    short* Hb  = CB;
    short* Wqb = CB + 2 * (size_t)SEG;
    short* Wkb = CB + 3 * (size_t)SEG;
    short* Wvb = CB + 4 * (size_t)SEG;
    short* Wob = CB + 5 * (size_t)SEG;
    short* Qb  = (short*)(ws + 50331648);
    short* Kb  = (short*)(ws + 67108864);
    short* Vb  = (short*)(ws + 83886080);   // [bh][d][s]
    short* AO  = Hb;                         // alias: hidden dead after gemm<0>
    float* tab = (float*)(ws + 100663296);

    cast_k<<<dim3(12288), dim3(256), 0, stream>>>(hs, wq, wk, wvp, wo, CB);
    rope_table_k<<<dim3(512), dim3(256), 0, stream>>>(tab);
    gemm_bt<0><<<dim3(32, 48), dim3(256), 0, stream>>>(
        Hb, Wqb, Wkb, Wvb, Qb, Kb, Vb, nullptr);
    rope_apply_k<<<dim3(2048), dim3(256), 0, stream>>>(Qb, Kb, tab);
    attn_k<<<dim3(32, 16), dim3(256), 0, stream>>>(Qb, Kb, Vb, AO);
    gemm_bt<1><<<dim3(32, 16), dim3(256), 0, stream>>>(
        AO, Wob, nullptr, nullptr, nullptr, nullptr, nullptr, out);
}

// Round 5
// 376.517 us; speedup vs baseline: 1.3492x; 1.3492x over previous
//
#include <hip/hip_runtime.h>
#include <hip/hip_bf16.h>

#define S_LEN  2048
#define BATCH  2
#define NH     16
#define HD     128
#define HIDDEN 2048
#define MROWS  (BATCH*S_LEN)   // 4096

typedef __attribute__((ext_vector_type(8))) short bf16x8;
typedef __attribute__((ext_vector_type(4))) short s16x4;
typedef __attribute__((ext_vector_type(4))) float f32x4;

__device__ __forceinline__ float bf2f(short s) {
    union { float f; unsigned int u; } v;
    v.u = ((unsigned int)(unsigned short)s) << 16;
    return v.f;
}
__device__ __forceinline__ short f2bf(float f) {
    union { float f; unsigned int u; } v;
    v.f = f;
    unsigned int r = v.u + 0x7fffu + ((v.u >> 16) & 1u);   // RNE, inputs never NaN
    return (short)(r >> 16);
}
__device__ __forceinline__ f32x4 mfma16(bf16x8 a, bf16x8 b, f32x4 c) {
    return __builtin_amdgcn_mfma_f32_16x16x32_bf16(a, b, c, 0, 0, 0);
}
__device__ __forceinline__ void gload16(const void* g, void* l) {
    __builtin_amdgcn_global_load_lds(
        (const __attribute__((address_space(1))) void*)g,
        (__attribute__((address_space(3))) void*)l, 16, 0, 0);
}

// ---------------------------------------------------------------------------
// Cast fp32 -> bf16: hidden (2 x 4M segs), wq, wk, wv, wo (1 seg each).
// ---------------------------------------------------------------------------
#define SEG (4194304)
__global__ void cast_k(const float* hs, const float* wq, const float* wk,
                       const float* wv, const float* wo, short* dst)
{
    size_t i = ((size_t)blockIdx.x * 256 + threadIdx.x) * 8;
    int seg = (int)(i >> 22);
    const float* s;
    size_t off;
    if (seg < 2)      { s = hs; off = i; }
    else if (seg == 2){ s = wq; off = i - 2 * (size_t)SEG; }
    else if (seg == 3){ s = wk; off = i - 3 * (size_t)SEG; }
    else if (seg == 4){ s = wv; off = i - 4 * (size_t)SEG; }
    else              { s = wo; off = i - 5 * (size_t)SEG; }
    f32x4 lo = *(const f32x4*)(s + off);
    f32x4 hi = *(const f32x4*)(s + off + 4);
    short v[8];
#pragma unroll
    for (int j = 0; j < 4; ++j) { v[j] = f2bf(lo[j]); v[4 + j] = f2bf(hi[j]); }
    *(bf16x8*)(dst + i) = *(bf16x8*)v;
}

// ---------------------------------------------------------------------------
// GEMM: C[M][N] = A[M][K] * W[N][K]^T, bf16 (m97 structure).
// ---------------------------------------------------------------------------
template<int MODE>
__global__ __launch_bounds__(256, 4)
void gemm_bt(const short* A, const short* W0, const short* W1, const short* W2,
             short* Oq, short* Ok, short* Ov, float* Of)
{
    __shared__ short smem[2 * 128 * 64];
    short* As = smem;
    short* Bs = smem + 128 * 64;

    const int tid  = threadIdx.x;
    const int lane = tid & 63;
    const int wv   = tid >> 6;
    const int wr   = wv >> 1, wc = wv & 1;
    const int fr   = lane & 15, fg = lane >> 4;

    const int mt = blockIdx.x;
    int nt = blockIdx.y;
    const short* W = W0;
    short* Ob = Oq;
    int osel = 0;
    if (MODE == 0) {
        osel = nt >> 4; nt &= 15;
        W  = (osel == 0) ? W0 : (osel == 1) ? W1 : W2;
        Ob = (osel == 0) ? Oq : (osel == 1) ? Ok : Ov;
    }
    const int row0 = mt * 128, col0 = nt * 128;
    const int sr = tid >> 3, sb = tid & 7;

    f32x4 acc[4][4];
#pragma unroll
    for (int m = 0; m < 4; ++m)
#pragma unroll
        for (int n = 0; n < 4; ++n) acc[m][n] = (f32x4){0.f, 0.f, 0.f, 0.f};

    for (int k0 = 0; k0 < HIDDEN; k0 += 64) {
        __syncthreads();
#pragma unroll
        for (int it = 0; it < 4; ++it) {
            int r = it * 32 + sr;
            gload16(A + (size_t)(row0 + r) * HIDDEN + k0 + ((sb ^ (r & 7)) * 8),
                    (char*)As + (it * 256 + wv * 64) * 16);
        }
#pragma unroll
        for (int it = 0; it < 4; ++it) {
            int r = it * 32 + sr;
            gload16(W + (size_t)(col0 + r) * HIDDEN + k0 + ((sb ^ (r & 7)) * 8),
                    (char*)Bs + (it * 256 + wv * 64) * 16);
        }
        __syncthreads();
#pragma unroll
        for (int ks = 0; ks < 2; ++ks) {
            bf16x8 a[4], b[4];
#pragma unroll
            for (int m = 0; m < 4; ++m) {
                int r = wr * 64 + m * 16 + fr;
                a[m] = *(const bf16x8*)&As[r * 64 + (((ks * 4 + fg) ^ (r & 7)) * 8)];
            }
#pragma unroll
            for (int n = 0; n < 4; ++n) {
                int r = wc * 64 + n * 16 + fr;
                b[n] = *(const bf16x8*)&Bs[r * 64 + (((ks * 4 + fg) ^ (r & 7)) * 8)];
            }
#pragma unroll
            for (int m = 0; m < 4; ++m)
#pragma unroll
                for (int n = 0; n < 4; ++n)
                    acc[m][n] = mfma16(a[m], b[n], acc[m][n]);
        }
    }

    if (MODE == 0 && osel == 2) {
        __syncthreads();
#pragma unroll
        for (int m = 0; m < 4; ++m)
#pragma unroll
            for (int j = 0; j < 4; ++j) {
                int row = wr * 64 + m * 16 + fg * 4 + j;
#pragma unroll
                for (int n = 0; n < 4; ++n) {
                    int col = wc * 64 + n * 16 + fr;
                    smem[col * 128 + (((row >> 3) ^ (col & 15)) * 8) + (row & 7)] =
                        f2bf(acc[m][n][j]);
                }
            }
        __syncthreads();
        const int b_ = row0 >> 11;
        const int bh = b_ * NH + nt;
        const int s0 = row0 & (S_LEN - 1);
#pragma unroll
        for (int it = 0; it < 8; ++it) {
            int c = it * 256 + tid;
            int d = c >> 4, sbk = c & 15;
            bf16x8 vv = *(const bf16x8*)&smem[d * 128 + ((sbk ^ (d & 15)) * 8)];
            *(bf16x8*)(Ov + ((size_t)bh * HD + d) * S_LEN + s0 + sbk * 8) = vv;
        }
    } else {
#pragma unroll
        for (int m = 0; m < 4; ++m)
#pragma unroll
            for (int j = 0; j < 4; ++j) {
                int mrow = row0 + wr * 64 + m * 16 + fg * 4 + j;
#pragma unroll
                for (int n = 0; n < 4; ++n) {
                    int col = col0 + wc * 64 + n * 16 + fr;
                    float val = acc[m][n][j];
                    if (MODE == 0) {
                        int b_ = mrow >> 11, s = mrow & (S_LEN - 1);
                        int h = col >> 7, d = col & (HD - 1);
                        Ob[((size_t)(b_ * NH + h) * S_LEN + s) * HD + d] = f2bf(val);
                    } else {
                        Of[(size_t)mrow * HIDDEN + col] = val;
                    }
                }
            }
    }
}

// ---------------------------------------------------------------------------
__global__ void rope_table_k(float* tab)
{
    int i = blockIdx.x * 256 + threadIdx.x;
    if (i >= S_LEN * 64) return;
    int s = i >> 6, d = i & 63;
    float inv = 1.0f / powf(10000.0f, (float)d * (1.0f / 64.0f));
    float ang = (float)s * inv;
    tab[2 * i]     = cosf(ang);
    tab[2 * i + 1] = sinf(ang);
}

__global__ void rope_apply_k(short* Q, short* K, const float* tab)
{
    int i = blockIdx.x * 256 + threadIdx.x;
    int d8 = i & 7;
    int s  = (i >> 3) & (S_LEN - 1);
    int bh = i >> 14;
    size_t base = ((size_t)bh * S_LEN + s) * HD + d8 * 8;
    const float* tp = tab + (s * 64 + d8 * 8) * 2;
    f32x4 t[4];
#pragma unroll
    for (int j = 0; j < 4; ++j) t[j] = *(const f32x4*)(tp + j * 4);

    bf16x8 q1 = *(bf16x8*)(Q + base), q2 = *(bf16x8*)(Q + base + 64);
    bf16x8 k1 = *(bf16x8*)(K + base), k2 = *(bf16x8*)(K + base + 64);
    short oq1[8], oq2[8], ok1[8], ok2[8];
    const float qs = 0.08838834764831845f;
#pragma unroll
    for (int j = 0; j < 8; ++j) {
        float c  = t[j >> 1][(j & 1) * 2];
        float sn = t[j >> 1][(j & 1) * 2 + 1];
        float a1 = bf2f(q1[j]), a2 = bf2f(q2[j]);
        oq1[j] = f2bf((a1 * c - a2 * sn) * qs);
        oq2[j] = f2bf((a2 * c + a1 * sn) * qs);
        float b1 = bf2f(k1[j]), b2 = bf2f(k2[j]);
        ok1[j] = f2bf(b1 * c - b2 * sn);
        ok2[j] = f2bf(b2 * c + b1 * sn);
    }
    *(bf16x8*)(Q + base)      = *(bf16x8*)oq1;
    *(bf16x8*)(Q + base + 64) = *(bf16x8*)oq2;
    *(bf16x8*)(K + base)      = *(bf16x8*)ok1;
    *(bf16x8*)(K + base + 64) = *(bf16x8*)ok2;
}

// ---------------------------------------------------------------------------
// Causal flash attention, swapped-operand (q lane-local) softmax.
// Block = 4 waves x 32 q-rows; processes q-tile p then q-tile 15-p
// (serial pairing -> uniform 34 KV-64 tiles/block). Grid: 256 blocks,
// bh = bid&31 (keeps one head's blocks on one XCD).
// K [bh][s][d]; V [bh][d][s] (transposed). KVBLK=64, K/V double-buffered.
// ---------------------------------------------------------------------------
__global__ __launch_bounds__(256, 1)
void attn_k(const short* Q, const short* K, const short* Vt, short* AO)
{
    __shared__ short Ks[2][64 * 128];   // 32 KB; 16B blk ^ (krow&15)
    __shared__ short Vs[2][128 * 64];   // 32 KB; 16B blk ^ (d&7)
    __shared__ short Ps[4][32 * 64];    // 16 KB per-wave P; 16B blk ^ (q&7)

    const int tid = threadIdx.x, lane = tid & 63, wv = tid >> 6;
    const int fr = lane & 15, fg = lane >> 4;
    const int bh = blockIdx.x & 31;
    const int p  = blockIdx.x >> 5;     // 0..7

    const short* Qb = Q  + (size_t)bh * S_LEN * HD;
    const short* Kb = K  + (size_t)bh * S_LEN * HD;
    const short* Vb = Vt + (size_t)bh * HD * S_LEN;
    const int b_ = bh >> 4, h = bh & 15;

#define STAGE(t, bufi)                                                          \
    do {                                                                        \
        const int kb_ = (t) * 64;                                               \
        _Pragma("unroll")                                                       \
        for (int i_ = 0; i_ < 4; ++i_) {                                        \
            int c_ = i_ * 256 + tid;                                            \
            int r_ = c_ >> 4, bb_ = c_ & 15;                                    \
            gload16(Kb + (size_t)(kb_ + r_) * HD + ((bb_ ^ (r_ & 15)) * 8),     \
                    (char*)&Ks[bufi][0] + (i_ * 256 + wv * 64) * 16);           \
        }                                                                       \
        _Pragma("unroll")                                                       \
        for (int i_ = 0; i_ < 4; ++i_) {                                        \
            int c_ = i_ * 256 + tid;                                            \
            int r_ = c_ >> 3, bb_ = c_ & 7;                                     \
            gload16(Vb + (size_t)r_ * S_LEN + kb_ + ((bb_ ^ (r_ & 7)) * 8),     \
                    (char*)&Vs[bufi][0] + (i_ * 256 + wv * 64) * 16);           \
        }                                                                       \
    } while (0)

#pragma unroll 1
    for (int phase = 0; phase < 2; ++phase) {
        const int qt = phase ? (15 - p) : p;
        const int qbase = qt * 128 + wv * 32;

        // Q fragments (scale already folded): B-operand layout
        bf16x8 qf[2][4];
#pragma unroll
        for (int mi = 0; mi < 2; ++mi)
#pragma unroll
            for (int ks = 0; ks < 4; ++ks)
                qf[mi][ks] = *(const bf16x8*)(Qb + (size_t)(qbase + mi * 16 + fr) * HD
                                              + ks * 32 + fg * 8);

        // O^T accumulator: oT[mi][nd][j] = O[q=qbase+mi*16+fr][d=nd*16+fg*4+j]
        f32x4 oT[2][8];
        float mrun[2], lrun[2];
#pragma unroll
        for (int mi = 0; mi < 2; ++mi) {
#pragma unroll
            for (int nd = 0; nd < 8; ++nd) oT[mi][nd] = (f32x4){0.f, 0.f, 0.f, 0.f};
            mrun[mi] = -1e30f;
            lrun[mi] = 0.f;
        }

        const int ntiles = (qt + 1) * 2;
        __syncthreads();                 // prev phase's LDS reads done
        STAGE(0, 0);

        for (int t = 0; t < ntiles; ++t) {
            const int buf = t & 1;
            __syncthreads();             // drains vmcnt -> buf ready
            if (t + 1 < ntiles) STAGE(t + 1, buf ^ 1);
            const int kb = t * 64;

            if (kb <= qbase + 31) {      // wave-uniform causal skip
                // ---- QK^T swapped: sc[ni][mi] = P^T tile ----
                f32x4 sc[4][2];
#pragma unroll
                for (int ni = 0; ni < 4; ++ni)
#pragma unroll
                    for (int mi = 0; mi < 2; ++mi) sc[ni][mi] = (f32x4){0.f, 0.f, 0.f, 0.f};
#pragma unroll
                for (int ks = 0; ks < 4; ++ks) {
                    bf16x8 kf[4];
#pragma unroll
                    for (int ni = 0; ni < 4; ++ni) {
                        int kc = ni * 16 + fr;
                        kf[ni] = *(const bf16x8*)&Ks[buf][kc * 128 + (((ks * 4 + fg) ^ (kc & 15)) * 8)];
                    }
#pragma unroll
                    for (int ni = 0; ni < 4; ++ni)
#pragma unroll
                        for (int mi = 0; mi < 2; ++mi)
                            sc[ni][mi] = mfma16(kf[ni], qf[mi][ks], sc[ni][mi]);
                }
                const bool need_mask = (kb + 63 > qbase);
                // ---- online softmax, q lane-local ----
#pragma unroll
                for (int mi = 0; mi < 2; ++mi) {
                    const int qrow = qbase + mi * 16 + fr;
                    if (need_mask) {
#pragma unroll
                        for (int ni = 0; ni < 4; ++ni)
#pragma unroll
                            for (int j = 0; j < 4; ++j) {
                                int kcol = kb + ni * 16 + fg * 4 + j;
                                if (kcol > qrow) sc[ni][mi][j] = -1e30f;
                            }
                    }
                    float mx = sc[0][mi][0];
#pragma unroll
                    for (int ni = 0; ni < 4; ++ni)
#pragma unroll
                        for (int j = 0; j < 4; ++j)
                            mx = fmaxf(mx, sc[ni][mi][j]);
                    mx = fmaxf(mx, __shfl_xor(mx, 16));
                    mx = fmaxf(mx, __shfl_xor(mx, 32));
                    if (mx > mrun[mi]) {
                        float scale = __expf(mrun[mi] - mx);
                        mrun[mi] = mx;
                        lrun[mi] *= scale;
#pragma unroll
                        for (int nd = 0; nd < 8; ++nd) {
#pragma unroll
                            for (int j = 0; j < 4; ++j) oT[mi][nd][j] *= scale;
                        }
                    }
                    const float m_ = mrun[mi];
                    float rs = 0.f;
                    const int q = mi * 16 + fr;
#pragma unroll
                    for (int ni = 0; ni < 4; ++ni) {
                        float e0 = __expf(sc[ni][mi][0] - m_);
                        float e1 = __expf(sc[ni][mi][1] - m_);
                        float e2 = __expf(sc[ni][mi][2] - m_);
                        float e3 = __expf(sc[ni][mi][3] - m_);
                        rs += (e0 + e1) + (e2 + e3);
                        s16x4 w;
                        w[0] = f2bf(e0); w[1] = f2bf(e1);
                        w[2] = f2bf(e2); w[3] = f2bf(e3);
                        int blk = ni * 2 + (fg >> 1);
                        *(s16x4*)&Ps[wv][q * 64 + ((blk ^ (q & 7)) * 8) + (fg & 1) * 4] = w;
                    }
                    rs += __shfl_xor(rs, 16);
                    rs += __shfl_xor(rs, 32);
                    lrun[mi] += rs;
                }
                asm volatile("s_waitcnt lgkmcnt(0)" ::: "memory");
                // ---- PV swapped: oT += V^T . P^T ----
                bf16x8 pf[2][2];
#pragma unroll
                for (int mi = 0; mi < 2; ++mi) {
                    const int q = mi * 16 + fr;
#pragma unroll
                    for (int ks = 0; ks < 2; ++ks)
                        pf[mi][ks] = *(const bf16x8*)&Ps[wv][q * 64 + (((ks * 4 + fg) ^ (q & 7)) * 8)];
                }
#pragma unroll
                for (int nd = 0; nd < 8; ++nd) {
                    const int d = nd * 16 + fr;
#pragma unroll
                    for (int ks = 0; ks < 2; ++ks) {
                        bf16x8 vf = *(const bf16x8*)&Vs[buf][d * 64 + (((ks * 4 + fg) ^ (d & 7)) * 8)];
#pragma unroll
                        for (int mi = 0; mi < 2; ++mi)
                            oT[mi][nd] = mfma16(vf, pf[mi][ks], oT[mi][nd]);
                    }
                }
            }
        }

        // ---- epilogue (lane-local normalize), write [b][s][h*128+d] ----
#pragma unroll
        for (int mi = 0; mi < 2; ++mi) {
            float inv = 1.0f / lrun[mi];
            int srow = qbase + mi * 16 + fr;
#pragma unroll
            for (int nd = 0; nd < 8; ++nd) {
                s16x4 w;
#pragma unroll
                for (int j = 0; j < 4; ++j) w[j] = f2bf(oT[mi][nd][j] * inv);
                *(s16x4*)(AO + ((size_t)b_ * S_LEN + srow) * HIDDEN
                          + h * HD + nd * 16 + fg * 4) = w;
            }
        }
    }
#undef STAGE
}

// ---------------------------------------------------------------------------
extern "C" void kernel_launch(void* const* d_in, const int* in_sizes, int n_in,
                              void* d_out, int out_size, void* d_ws, size_t ws_size,
                              hipStream_t stream)
{
    const float* hs = (const float*)d_in[0];
    const float* wq = (const float*)d_in[1];
    const float* wk = (const float*)d_in[2];
    const float* wvp = (const float*)d_in[3];
    const float* wo = (const float*)d_in[4];
    float* out = (float*)d_out;

    char* ws = (char*)d_ws;
    short* CB  = (short*)ws;
    short* Hb  = CB;
    short* Wqb = CB + 2 * (size_t)SEG;
    short* Wkb = CB + 3 * (size_t)SEG;
    short* Wvb = CB + 4 * (size_t)SEG;
    short* Wob = CB + 5 * (size_t)SEG;
    short* Qb  = (short*)(ws + 50331648);
    short* Kb  = (short*)(ws + 67108864);
    short* Vb  = (short*)(ws + 83886080);   // [bh][d][s]
    short* AO  = Hb;                         // alias: hidden dead after gemm<0>
    float* tab = (float*)(ws + 100663296);

    cast_k<<<dim3(12288), dim3(256), 0, stream>>>(hs, wq, wk, wvp, wo, CB);
    rope_table_k<<<dim3(512), dim3(256), 0, stream>>>(tab);
    gemm_bt<0><<<dim3(32, 48), dim3(256), 0, stream>>>(
        Hb, Wqb, Wkb, Wvb, Qb, Kb, Vb, nullptr);
    rope_apply_k<<<dim3(2048), dim3(256), 0, stream>>>(Qb, Kb, tab);
    attn_k<<<dim3(256), dim3(256), 0, stream>>>(Qb, Kb, Vb, AO);
    gemm_bt<1><<<dim3(32, 16), dim3(256), 0, stream>>>(
        AO, Wob, nullptr, nullptr, nullptr, nullptr, nullptr, out);
}

// Round 6
// 355.272 us; speedup vs baseline: 1.4299x; 1.0598x over previous
//
#include <hip/hip_runtime.h>
#include <hip/hip_bf16.h>

#define S_LEN  2048
#define BATCH  2
#define NH     16
#define HD     128
#define HIDDEN 2048
#define MROWS  (BATCH*S_LEN)   // 4096

typedef __attribute__((ext_vector_type(8))) short bf16x8;
typedef __attribute__((ext_vector_type(4))) short s16x4;
typedef __attribute__((ext_vector_type(4))) float f32x4;

__device__ __forceinline__ float bf2f(short s) {
    union { float f; unsigned int u; } v;
    v.u = ((unsigned int)(unsigned short)s) << 16;
    return v.f;
}
__device__ __forceinline__ short f2bf(float f) {
    union { float f; unsigned int u; } v;
    v.f = f;
    unsigned int r = v.u + 0x7fffu + ((v.u >> 16) & 1u);   // RNE, inputs never NaN
    return (short)(r >> 16);
}
__device__ __forceinline__ f32x4 mfma16(bf16x8 a, bf16x8 b, f32x4 c) {
    return __builtin_amdgcn_mfma_f32_16x16x32_bf16(a, b, c, 0, 0, 0);
}
__device__ __forceinline__ void gload16(const void* g, void* l) {
    __builtin_amdgcn_global_load_lds(
        (const __attribute__((address_space(1))) void*)g,
        (__attribute__((address_space(3))) void*)l, 16, 0, 0);
}

// ---------------------------------------------------------------------------
// Cast fp32 -> bf16: hidden (2 x 4M segs), wq, wk, wv, wo (1 seg each).
// ---------------------------------------------------------------------------
#define SEG (4194304)
__global__ void cast_k(const float* hs, const float* wq, const float* wk,
                       const float* wv, const float* wo, short* dst)
{
    size_t i = ((size_t)blockIdx.x * 256 + threadIdx.x) * 8;
    int seg = (int)(i >> 22);
    const float* s;
    size_t off;
    if (seg < 2)      { s = hs; off = i; }
    else if (seg == 2){ s = wq; off = i - 2 * (size_t)SEG; }
    else if (seg == 3){ s = wk; off = i - 3 * (size_t)SEG; }
    else if (seg == 4){ s = wv; off = i - 4 * (size_t)SEG; }
    else              { s = wo; off = i - 5 * (size_t)SEG; }
    f32x4 lo = *(const f32x4*)(s + off);
    f32x4 hi = *(const f32x4*)(s + off + 4);
    short v[8];
#pragma unroll
    for (int j = 0; j < 4; ++j) { v[j] = f2bf(lo[j]); v[4 + j] = f2bf(hi[j]); }
    *(bf16x8*)(dst + i) = *(bf16x8*)v;
}

// ---------------------------------------------------------------------------
// GEMM: C[M][N] = A[M][K] * W[N][K]^T, bf16 (m97 structure).
// ---------------------------------------------------------------------------
template<int MODE>
__global__ __launch_bounds__(256, 4)
void gemm_bt(const short* A, const short* W0, const short* W1, const short* W2,
             short* Oq, short* Ok, short* Ov, float* Of)
{
    __shared__ short smem[2 * 128 * 64];
    short* As = smem;
    short* Bs = smem + 128 * 64;

    const int tid  = threadIdx.x;
    const int lane = tid & 63;
    const int wv   = tid >> 6;
    const int wr   = wv >> 1, wc = wv & 1;
    const int fr   = lane & 15, fg = lane >> 4;

    const int mt = blockIdx.x;
    int nt = blockIdx.y;
    const short* W = W0;
    short* Ob = Oq;
    int osel = 0;
    if (MODE == 0) {
        osel = nt >> 4; nt &= 15;
        W  = (osel == 0) ? W0 : (osel == 1) ? W1 : W2;
        Ob = (osel == 0) ? Oq : (osel == 1) ? Ok : Ov;
    }
    const int row0 = mt * 128, col0 = nt * 128;
    const int sr = tid >> 3, sb = tid & 7;

    f32x4 acc[4][4];
#pragma unroll
    for (int m = 0; m < 4; ++m)
#pragma unroll
        for (int n = 0; n < 4; ++n) acc[m][n] = (f32x4){0.f, 0.f, 0.f, 0.f};

    for (int k0 = 0; k0 < HIDDEN; k0 += 64) {
        __syncthreads();
#pragma unroll
        for (int it = 0; it < 4; ++it) {
            int r = it * 32 + sr;
            gload16(A + (size_t)(row0 + r) * HIDDEN + k0 + ((sb ^ (r & 7)) * 8),
                    (char*)As + (it * 256 + wv * 64) * 16);
        }
#pragma unroll
        for (int it = 0; it < 4; ++it) {
            int r = it * 32 + sr;
            gload16(W + (size_t)(col0 + r) * HIDDEN + k0 + ((sb ^ (r & 7)) * 8),
                    (char*)Bs + (it * 256 + wv * 64) * 16);
        }
        __syncthreads();
#pragma unroll
        for (int ks = 0; ks < 2; ++ks) {
            bf16x8 a[4], b[4];
#pragma unroll
            for (int m = 0; m < 4; ++m) {
                int r = wr * 64 + m * 16 + fr;
                a[m] = *(const bf16x8*)&As[r * 64 + (((ks * 4 + fg) ^ (r & 7)) * 8)];
            }
#pragma unroll
            for (int n = 0; n < 4; ++n) {
                int r = wc * 64 + n * 16 + fr;
                b[n] = *(const bf16x8*)&Bs[r * 64 + (((ks * 4 + fg) ^ (r & 7)) * 8)];
            }
#pragma unroll
            for (int m = 0; m < 4; ++m)
#pragma unroll
                for (int n = 0; n < 4; ++n)
                    acc[m][n] = mfma16(a[m], b[n], acc[m][n]);
        }
    }

    if (MODE == 0 && osel == 2) {
        __syncthreads();
#pragma unroll
        for (int m = 0; m < 4; ++m)
#pragma unroll
            for (int j = 0; j < 4; ++j) {
                int row = wr * 64 + m * 16 + fg * 4 + j;
#pragma unroll
                for (int n = 0; n < 4; ++n) {
                    int col = wc * 64 + n * 16 + fr;
                    smem[col * 128 + (((row >> 3) ^ (col & 15)) * 8) + (row & 7)] =
                        f2bf(acc[m][n][j]);
                }
            }
        __syncthreads();
        const int b_ = row0 >> 11;
        const int bh = b_ * NH + nt;
        const int s0 = row0 & (S_LEN - 1);
#pragma unroll
        for (int it = 0; it < 8; ++it) {
            int c = it * 256 + tid;
            int d = c >> 4, sbk = c & 15;
            bf16x8 vv = *(const bf16x8*)&smem[d * 128 + ((sbk ^ (d & 15)) * 8)];
            *(bf16x8*)(Ov + ((size_t)bh * HD + d) * S_LEN + s0 + sbk * 8) = vv;
        }
    } else {
#pragma unroll
        for (int m = 0; m < 4; ++m)
#pragma unroll
            for (int j = 0; j < 4; ++j) {
                int mrow = row0 + wr * 64 + m * 16 + fg * 4 + j;
#pragma unroll
                for (int n = 0; n < 4; ++n) {
                    int col = col0 + wc * 64 + n * 16 + fr;
                    float val = acc[m][n][j];
                    if (MODE == 0) {
                        int b_ = mrow >> 11, s = mrow & (S_LEN - 1);
                        int h = col >> 7, d = col & (HD - 1);
                        Ob[((size_t)(b_ * NH + h) * S_LEN + s) * HD + d] = f2bf(val);
                    } else {
                        Of[(size_t)mrow * HIDDEN + col] = val;
                    }
                }
            }
    }
}

// ---------------------------------------------------------------------------
__global__ void rope_table_k(float* tab)
{
    int i = blockIdx.x * 256 + threadIdx.x;
    if (i >= S_LEN * 64) return;
    int s = i >> 6, d = i & 63;
    float inv = 1.0f / powf(10000.0f, (float)d * (1.0f / 64.0f));
    float ang = (float)s * inv;
    tab[2 * i]     = cosf(ang);
    tab[2 * i + 1] = sinf(ang);
}

__global__ void rope_apply_k(short* Q, short* K, const float* tab)
{
    int i = blockIdx.x * 256 + threadIdx.x;
    int d8 = i & 7;
    int s  = (i >> 3) & (S_LEN - 1);
    int bh = i >> 14;
    size_t base = ((size_t)bh * S_LEN + s) * HD + d8 * 8;
    const float* tp = tab + (s * 64 + d8 * 8) * 2;
    f32x4 t[4];
#pragma unroll
    for (int j = 0; j < 4; ++j) t[j] = *(const f32x4*)(tp + j * 4);

    bf16x8 q1 = *(bf16x8*)(Q + base), q2 = *(bf16x8*)(Q + base + 64);
    bf16x8 k1 = *(bf16x8*)(K + base), k2 = *(bf16x8*)(K + base + 64);
    short oq1[8], oq2[8], ok1[8], ok2[8];
    const float qs = 0.08838834764831845f;
#pragma unroll
    for (int j = 0; j < 8; ++j) {
        float c  = t[j >> 1][(j & 1) * 2];
        float sn = t[j >> 1][(j & 1) * 2 + 1];
        float a1 = bf2f(q1[j]), a2 = bf2f(q2[j]);
        oq1[j] = f2bf((a1 * c - a2 * sn) * qs);
        oq2[j] = f2bf((a2 * c + a1 * sn) * qs);
        float b1 = bf2f(k1[j]), b2 = bf2f(k2[j]);
        ok1[j] = f2bf(b1 * c - b2 * sn);
        ok2[j] = f2bf(b2 * c + b1 * sn);
    }
    *(bf16x8*)(Q + base)      = *(bf16x8*)oq1;
    *(bf16x8*)(Q + base + 64) = *(bf16x8*)oq2;
    *(bf16x8*)(K + base)      = *(bf16x8*)ok1;
    *(bf16x8*)(K + base + 64) = *(bf16x8*)ok2;
}

// ---------------------------------------------------------------------------
// Causal flash attention, swapped-operand, P kept fully in registers via
// k-permuted QK^T tiles (kf row remap makes the MFMA C-layout == PV B-operand
// layout; no cross-lane P movement, no P LDS).
// Grid: 512 blocks = 32 bh x 8 pairs x 2 q-halves. Block = 4 waves x 16 q-rows
// = 64 q-rows; processes q-tile p then 15-p (balanced). LDS 64 KB -> 2 blk/CU.
// K [bh][s][d]; V [bh][d][s]. KVBLK=64, K/V double-buffered.
// Ks store swizzle s(r) = (r&3)|(((r>>3)&3)<<2); read side s(rk)==fr.
// ---------------------------------------------------------------------------
__global__ __launch_bounds__(256, 2)
void attn_k(const short* Q, const short* K, const short* Vt, short* AO)
{
    __shared__ short Ks[2][64 * 128];   // 32 KB
    __shared__ short Vs[2][128 * 64];   // 32 KB

    const int tid = threadIdx.x, lane = tid & 63, wv = tid >> 6;
    const int fr = lane & 15, fg = lane >> 4;
    const int bid = blockIdx.x;
    const int bh   = bid & 31;
    const int sub  = bid >> 5;          // 0..15
    const int p    = sub >> 1;          // 0..7
    const int half = sub & 1;

    const short* Qb = Q  + (size_t)bh * S_LEN * HD;
    const short* Kb = K  + (size_t)bh * S_LEN * HD;
    const short* Vb = Vt + (size_t)bh * HD * S_LEN;
    const int b_ = bh >> 4, h = bh & 15;

#define SWK(r) (((r) & 3) | ((((r) >> 3) & 3) << 2))
#define STAGE(t, bufi)                                                          \
    do {                                                                        \
        const int kb_ = (t) * 64;                                               \
        _Pragma("unroll")                                                       \
        for (int i_ = 0; i_ < 4; ++i_) {                                        \
            int c_ = i_ * 256 + tid;                                            \
            int r_ = c_ >> 4, bb_ = c_ & 15;                                    \
            gload16(Kb + (size_t)(kb_ + r_) * HD + ((bb_ ^ SWK(r_)) * 8),       \
                    (char*)&Ks[bufi][0] + (i_ * 256 + wv * 64) * 16);           \
        }                                                                       \
        _Pragma("unroll")                                                       \
        for (int i_ = 0; i_ < 4; ++i_) {                                        \
            int c_ = i_ * 256 + tid;                                            \
            int r_ = c_ >> 3, bb_ = c_ & 7;                                     \
            gload16(Vb + (size_t)r_ * S_LEN + kb_ + ((bb_ ^ (r_ & 7)) * 8),     \
                    (char*)&Vs[bufi][0] + (i_ * 256 + wv * 64) * 16);           \
        }                                                                       \
    } while (0)

#pragma unroll 1
    for (int phase = 0; phase < 2; ++phase) {
        const int qt = phase ? (15 - p) : p;
        const int qbase = qt * 128 + half * 64 + wv * 16;

        // Q fragments (1/sqrt(128) pre-folded): B-operand, 16 q-rows
        bf16x8 qf[4];
#pragma unroll
        for (int ks = 0; ks < 4; ++ks)
            qf[ks] = *(const bf16x8*)(Qb + (size_t)(qbase + fr) * HD
                                      + ks * 32 + fg * 8);

        // O^T accumulator: oT[nd][j] = O[q=qbase+fr][d=nd*16+fg*4+j]
        f32x4 oT[8];
#pragma unroll
        for (int nd = 0; nd < 8; ++nd) oT[nd] = (f32x4){0.f, 0.f, 0.f, 0.f};
        float mrun = -1e30f, lrun = 0.f;

        const int ntiles = qt * 2 + 1 + half;
        __syncthreads();                 // prev phase's LDS reads done
        STAGE(0, 0);

        for (int t = 0; t < ntiles; ++t) {
            const int buf = t & 1;
            __syncthreads();             // drains vmcnt -> buf ready
            if (t + 1 < ntiles) STAGE(t + 1, buf ^ 1);
            const int kb = t * 64;

            if (kb <= qbase + 15) {      // wave-uniform causal skip
                // ---- QK^T, k-permuted tiles: sc[ni][j] = P^T[k][q=fr] with
                //      k = (ni&1)*32 + fg*8 + (ni>>1)*4 + j
                f32x4 sc[4];
#pragma unroll
                for (int ni = 0; ni < 4; ++ni) sc[ni] = (f32x4){0.f, 0.f, 0.f, 0.f};
                __builtin_amdgcn_s_setprio(1);
#pragma unroll
                for (int ks = 0; ks < 4; ++ks) {
                    bf16x8 kf[4];
#pragma unroll
                    for (int ni = 0; ni < 4; ++ni) {
                        int rk = ((ni & 1) << 5) + ((fr >> 2) << 3)
                               + ((ni >> 1) << 2) + (fr & 3);
                        kf[ni] = *(const bf16x8*)&Ks[buf][rk * 128
                                     + (((ks * 4 + fg) ^ fr) * 8)];
                    }
#pragma unroll
                    for (int ni = 0; ni < 4; ++ni)
                        sc[ni] = mfma16(kf[ni], qf[ks], sc[ni]);
                }
                __builtin_amdgcn_s_setprio(0);
                const int qrow = qbase + fr;
                if (kb + 63 > qbase) {   // masking tile
#pragma unroll
                    for (int ni = 0; ni < 4; ++ni)
#pragma unroll
                        for (int j = 0; j < 4; ++j) {
                            int kcol = kb + ((ni & 1) << 5) + (fg << 3)
                                     + ((ni >> 1) << 2) + j;
                            if (kcol > qrow) sc[ni][j] = -1e30f;
                        }
                }
                // ---- online softmax, q lane-local ----
                float mx = sc[0][0];
#pragma unroll
                for (int ni = 0; ni < 4; ++ni)
#pragma unroll
                    for (int j = 0; j < 4; ++j) mx = fmaxf(mx, sc[ni][j]);
                mx = fmaxf(mx, __shfl_xor(mx, 16));
                mx = fmaxf(mx, __shfl_xor(mx, 32));
                if (mx > mrun) {
                    float scale = __expf(mrun - mx);
                    mrun = mx;
                    lrun *= scale;
#pragma unroll
                    for (int nd = 0; nd < 8; ++nd)
#pragma unroll
                        for (int j = 0; j < 4; ++j) oT[nd][j] *= scale;
                }
                float rs = 0.f;
                short pw[16];
#pragma unroll
                for (int ni = 0; ni < 4; ++ni)
#pragma unroll
                    for (int j = 0; j < 4; ++j) {
                        float pe = __expf(sc[ni][j] - mrun);
                        rs += pe;
                        pw[((ni & 1) << 3) + ((ni >> 1) << 2) + j] = f2bf(pe);
                    }
                bf16x8 pf0 = *(bf16x8*)&pw[0];
                bf16x8 pf1 = *(bf16x8*)&pw[8];
                rs += __shfl_xor(rs, 16);
                rs += __shfl_xor(rs, 32);
                lrun += rs;
                // ---- PV: oT += V^T . P^T, all operands lane-local ----
                __builtin_amdgcn_s_setprio(1);
#pragma unroll
                for (int nd = 0; nd < 8; ++nd) {
                    const int d = nd * 16 + fr;
                    bf16x8 vf0 = *(const bf16x8*)&Vs[buf][d * 64 + ((fg ^ (d & 7)) * 8)];
                    bf16x8 vf1 = *(const bf16x8*)&Vs[buf][d * 64 + (((4 + fg) ^ (d & 7)) * 8)];
                    oT[nd] = mfma16(vf0, pf0, oT[nd]);
                    oT[nd] = mfma16(vf1, pf1, oT[nd]);
                }
                __builtin_amdgcn_s_setprio(0);
            }
        }

        // ---- epilogue (lane-local normalize), write [b][s][h*128+d] ----
        float inv = 1.0f / lrun;
        int srow = qbase + fr;
#pragma unroll
        for (int nd = 0; nd < 8; ++nd) {
            s16x4 w;
#pragma unroll
            for (int j = 0; j < 4; ++j) w[j] = f2bf(oT[nd][j] * inv);
            *(s16x4*)(AO + ((size_t)b_ * S_LEN + srow) * HIDDEN
                      + h * HD + nd * 16 + fg * 4) = w;
        }
    }
#undef STAGE
#undef SWK
}

// ---------------------------------------------------------------------------
extern "C" void kernel_launch(void* const* d_in, const int* in_sizes, int n_in,
                              void* d_out, int out_size, void* d_ws, size_t ws_size,
                              hipStream_t stream)
{
    const float* hs = (const float*)d_in[0];
    const float* wq = (const float*)d_in[1];
    const float* wk = (const float*)d_in[2];
    const float* wvp = (const float*)d_in[3];
    const float* wo = (const float*)d_in[4];
    float* out = (float*)d_out;

    char* ws = (char*)d_ws;
    short* CB  = (short*)ws;
    short* Hb  = CB;
    short* Wqb = CB + 2 * (size_t)SEG;
    short* Wkb = CB + 3 * (size_t)SEG;
    short* Wvb = CB + 4 * (size_t)SEG;
    short* Wob = CB + 5 * (size_t)SEG;
    short* Qb  = (short*)(ws + 50331648);
    short* Kb  = (short*)(ws + 67108864);
    short* Vb  = (short*)(ws + 83886080);   // [bh][d][s]
    short* AO  = Hb;                         // alias: hidden dead after gemm<0>
    float* tab = (float*)(ws + 100663296);

    cast_k<<<dim3(12288), dim3(256), 0, stream>>>(hs, wq, wk, wvp, wo, CB);
    rope_table_k<<<dim3(512), dim3(256), 0, stream>>>(tab);
    gemm_bt<0><<<dim3(32, 48), dim3(256), 0, stream>>>(
        Hb, Wqb, Wkb, Wvb, Qb, Kb, Vb, nullptr);
    rope_apply_k<<<dim3(2048), dim3(256), 0, stream>>>(Qb, Kb, tab);
    attn_k<<<dim3(512), dim3(256), 0, stream>>>(Qb, Kb, Vb, AO);
    gemm_bt<1><<<dim3(32, 16), dim3(256), 0, stream>>>(
        AO, Wob, nullptr, nullptr, nullptr, nullptr, nullptr, out);
}